// Round 15
// baseline (81.085 us; speedup 1.0000x reference)
//
#include <hip/hip_runtime.h>

typedef unsigned short u16;
typedef __attribute__((ext_vector_type(8))) short bf16x8;  // 8 bf16 = 16 B
typedef __attribute__((ext_vector_type(8))) short s16x8;
typedef __attribute__((ext_vector_type(4))) float f32x4;

constexpr int kN  = 8192;
constexpr int kD  = 256;
constexpr int kDA = 384;   // augmented+padded feature dim: [x(256) | 1 | u | 0-pad]

#define GLOAD_LDS16(gptr, ldsptr)                                                   \
  __builtin_amdgcn_global_load_lds(                                                 \
      (const __attribute__((address_space(1))) unsigned int*)(gptr),                \
      (__attribute__((address_space(3))) unsigned int*)(ldsptr), 16, 0, 0)

__device__ __forceinline__ u16 f2bf(float f) {
  union { float f; unsigned u; } c; c.f = f;
  unsigned r = c.u + 0x7fffu + ((c.u >> 16) & 1u);
  return (u16)(r >> 16);
}

// ---------------------------------------------------------------------------
// K1 prep: bf16 convert + augment (col256=1, col257=u, rest 0), uarr, buckets.
// One wave per row, 4 rows/block (R1-proven shape).
// ---------------------------------------------------------------------------
__global__ __launch_bounds__(256) void prep_kernel(
    const float* __restrict__ samples, const float* __restrict__ input1,
    u16* __restrict__ Xaug, float* __restrict__ uarr,
    int* __restrict__ bcount, int* __restrict__ brows)
{
  const int row  = blockIdx.x * 4 + (threadIdx.x >> 6);
  const int lane = threadIdx.x & 63;

  const float4 v = *(const float4*)(samples + (size_t)row * kD + lane * 4);
  u16 h[4] = {f2bf(v.x), f2bf(v.y), f2bf(v.z), f2bf(v.w)};
  *(ushort4*)(Xaug + (size_t)row * kDA + lane * 4) = make_ushort4(h[0], h[1], h[2], h[3]);

  float ss = v.x * v.x + v.y * v.y + v.z * v.z + v.w * v.w;
#pragma unroll
  for (int m = 32; m >= 1; m >>= 1) ss += __shfl_xor(ss, m);
  const float u = ss * (1.0f / 256.0f);

  // augmented cols 256..383: lane l owns cols 256+2l, 257+2l
  ushort2 augv;
  augv.x = (lane == 0) ? (u16)0x3F80 : (u16)0;   // bf16(1.0)
  augv.y = (lane == 0) ? f2bf(u) : (u16)0;
  *(ushort2*)(Xaug + (size_t)row * kDA + 256 + lane * 2) = augv;

  if (lane == 0) {
    uarr[row] = u;
    int id  = (int)input1[row * 32 + 7];   // input1[i,0,F-1]
    int pos = atomicAdd(&bcount[id], 1);
    if (pos < 128) brows[id * 128 + pos] = row;
  }
}

// ---------------------------------------------------------------------------
// K1b transpose: XT[d][j] = Xaug[j][d], 64-row tiles via LDS.
// ---------------------------------------------------------------------------
__global__ __launch_bounds__(256) void transpose_kernel(
    const u16* __restrict__ Xaug, u16* __restrict__ XT)
{
  __shared__ u16 T[64 * 400];  // 64 rows x 384 cols, padded stride 400
  const int blk = blockIdx.x;  // rows blk*64 .. +63
  const int tid = threadIdx.x;

#pragma unroll
  for (int it = 0; it < 12; ++it) {
    const int idx = it * 256 + tid;          // 3072 ushort8 chunks
    const int r   = idx / 48;                // 48 chunks per row (384/8)
    const int c8  = idx % 48;
    *(s16x8*)(T + r * 400 + c8 * 8) =
        *(const s16x8*)(Xaug + (size_t)(blk * 64 + r) * kDA + c8 * 8);
  }
  __syncthreads();

#pragma unroll
  for (int it = 0; it < 12; ++it) {
    const int idx = it * 256 + tid;          // 3072 ushort8 chunks of XT
    const int d   = idx >> 3;                // 384 d-rows
    const int c8  = idx & 7;                 // 8 chunks of 8 cols
    s16x8 o;
#pragma unroll
    for (int k = 0; k < 8; ++k) o[k] = (short)T[(c8 * 8 + k) * 400 + d];
    *(s16x8*)(XT + (size_t)d * kN + blk * 64 + c8 * 8) = o;
  }
}

// ---------------------------------------------------------------------------
// K2 syrk: M'[384][384] partials = XT . XT^T over K-chunk of 256.
// Grid (9 tiles, 32 kchunks). R10-proven 128^2 body, plain-store epilogue.
// ---------------------------------------------------------------------------
__global__ __launch_bounds__(256, 2) void syrk_kernel(
    const u16* __restrict__ XT, float* __restrict__ slab)
{
  __shared__ u16 Abuf[128 * 64];
  __shared__ u16 Bbuf[128 * 64];

  const int tid = threadIdx.x, lane = tid & 63, w = tid >> 6;
  const int wm = w >> 1, wn = w & 1, llo = lane & 15, lhi = lane >> 4;
  const int tile = blockIdx.x, kc = blockIdx.y;
  const int tr = tile / 3, tc = tile % 3;
  const int i0 = tr * 128, j0 = tc * 128, kb = kc * 256;
  const int sr = tid >> 3, sl = tid & 7;

  f32x4 acc[4][4];
#pragma unroll
  for (int mi = 0; mi < 4; ++mi)
#pragma unroll
    for (int ni = 0; ni < 4; ++ni) acc[mi][ni] = {0.f, 0.f, 0.f, 0.f};

#pragma unroll
  for (int kt = 0; kt < 4; ++kt) {
    const int k0 = kb + kt * 64;
#pragma unroll
    for (int cc = 0; cc < 4; ++cc) {
      const int rr = cc * 32 + sr;
      const int ksl = sl ^ (rr & 7);
      GLOAD_LDS16(XT + (size_t)(i0 + rr) * kN + k0 + ksl * 8, Abuf + rr * 64 + sl * 8);
      GLOAD_LDS16(XT + (size_t)(j0 + rr) * kN + k0 + ksl * 8, Bbuf + rr * 64 + sl * 8);
    }
    __syncthreads();
#pragma unroll
    for (int k32 = 0; k32 < 2; ++k32) {
      bf16x8 a[4], bv[4];
#pragma unroll
      for (int mi = 0; mi < 4; ++mi) {
        const int ra = wm * 64 + mi * 16 + llo;
        const int slot = (k32 * 4 + lhi) ^ (ra & 7);
        a[mi] = *(const bf16x8*)(Abuf + ra * 64 + slot * 8);
      }
#pragma unroll
      for (int ni = 0; ni < 4; ++ni) {
        const int rb = wn * 64 + ni * 16 + llo;
        const int slot = (k32 * 4 + lhi) ^ (rb & 7);
        bv[ni] = *(const bf16x8*)(Bbuf + rb * 64 + slot * 8);
      }
      __builtin_amdgcn_s_setprio(1);
#pragma unroll
      for (int mi = 0; mi < 4; ++mi)
#pragma unroll
        for (int ni = 0; ni < 4; ++ni)
          acc[mi][ni] = __builtin_amdgcn_mfma_f32_16x16x32_bf16(
              a[mi], bv[ni], acc[mi][ni], 0, 0, 0);
      __builtin_amdgcn_s_setprio(0);
    }
    __syncthreads();
  }

  float* dst = slab + (size_t)(kc * 9 + tile) * 16384;
#pragma unroll
  for (int mi = 0; mi < 4; ++mi)
#pragma unroll
    for (int ni = 0; ni < 4; ++ni)
#pragma unroll
      for (int rr = 0; rr < 4; ++rr) {
        const int r = wm * 64 + mi * 16 + lhi * 4 + rr;
        const int c = wn * 64 + ni * 16 + llo;
        dst[r * 128 + c] = acc[mi][ni][rr];
      }
}

// ---------------------------------------------------------------------------
// K3 reduceM: M'[d][c] = sum of 32 k-chunk slabs. Emit Mhat bf16 (diag and
// cols>=256 and rows>=258 zeroed), Mdiag f32, consts {U1, U2}.
// ---------------------------------------------------------------------------
__global__ __launch_bounds__(256) void reduceM_kernel(
    const float* __restrict__ slab, u16* __restrict__ Mhat,
    float* __restrict__ Mdiag, float* __restrict__ consts)
{
  const int e = blockIdx.x * 256 + threadIdx.x;  // 384*384 elements
  const int d = e / kDA, c = e % kDA;
  const int tr = d >> 7, tc = c >> 7, r = d & 127, cl = c & 127;
  float s = 0.f;
#pragma unroll
  for (int kc = 0; kc < 32; ++kc)
    s += slab[(size_t)(kc * 9 + tr * 3 + tc) * 16384 + r * 128 + cl];

  Mhat[e] = (d < 258 && c < 256 && d != c) ? f2bf(s) : (u16)0;
  if (d == c && d < 256) Mdiag[d] = s;
  if (d == 257 && c == 256) consts[0] = s;  // U1 = sum u_j
  if (d == 257 && c == 257) consts[1] = s;  // U2 = sum u_j^2
}

// ---------------------------------------------------------------------------
// K4 pgemm: P[i][d] = sum_e Xaug[i][e] * Mhat[d][e]; K=384 split in 2 slabs.
// Grid (64 i-strips, 3 d-tiles, 2 k-splits). Same proven body.
// ---------------------------------------------------------------------------
__global__ __launch_bounds__(256, 2) void pgemm_kernel(
    const u16* __restrict__ Xaug, const u16* __restrict__ Mhat,
    float* __restrict__ Pslab)
{
  __shared__ u16 Abuf[128 * 64];
  __shared__ u16 Bbuf[128 * 64];

  const int tid = threadIdx.x, lane = tid & 63, w = tid >> 6;
  const int wm = w >> 1, wn = w & 1, llo = lane & 15, lhi = lane >> 4;
  const int i0 = blockIdx.x * 128, j0 = blockIdx.y * 128;
  const int kb = blockIdx.z * 192;
  const int sr = tid >> 3, sl = tid & 7;

  f32x4 acc[4][4];
#pragma unroll
  for (int mi = 0; mi < 4; ++mi)
#pragma unroll
    for (int ni = 0; ni < 4; ++ni) acc[mi][ni] = {0.f, 0.f, 0.f, 0.f};

#pragma unroll
  for (int kt = 0; kt < 3; ++kt) {
    const int k0 = kb + kt * 64;
#pragma unroll
    for (int cc = 0; cc < 4; ++cc) {
      const int rr = cc * 32 + sr;
      const int ksl = sl ^ (rr & 7);
      GLOAD_LDS16(Xaug + (size_t)(i0 + rr) * kDA + k0 + ksl * 8, Abuf + rr * 64 + sl * 8);
      GLOAD_LDS16(Mhat + (size_t)(j0 + rr) * kDA + k0 + ksl * 8, Bbuf + rr * 64 + sl * 8);
    }
    __syncthreads();
#pragma unroll
    for (int k32 = 0; k32 < 2; ++k32) {
      bf16x8 a[4], bv[4];
#pragma unroll
      for (int mi = 0; mi < 4; ++mi) {
        const int ra = wm * 64 + mi * 16 + llo;
        const int slot = (k32 * 4 + lhi) ^ (ra & 7);
        a[mi] = *(const bf16x8*)(Abuf + ra * 64 + slot * 8);
      }
#pragma unroll
      for (int ni = 0; ni < 4; ++ni) {
        const int rb = wn * 64 + ni * 16 + llo;
        const int slot = (k32 * 4 + lhi) ^ (rb & 7);
        bv[ni] = *(const bf16x8*)(Bbuf + rb * 64 + slot * 8);
      }
      __builtin_amdgcn_s_setprio(1);
#pragma unroll
      for (int mi = 0; mi < 4; ++mi)
#pragma unroll
        for (int ni = 0; ni < 4; ++ni)
          acc[mi][ni] = __builtin_amdgcn_mfma_f32_16x16x32_bf16(
              a[mi], bv[ni], acc[mi][ni], 0, 0, 0);
      __builtin_amdgcn_s_setprio(0);
    }
    __syncthreads();
  }

  float* dst = Pslab + (size_t)blockIdx.z * kN * kDA;
#pragma unroll
  for (int mi = 0; mi < 4; ++mi)
#pragma unroll
    for (int ni = 0; ni < 4; ++ni)
#pragma unroll
      for (int rr = 0; rr < 4; ++rr) {
        const int r = wm * 64 + mi * 16 + lhi * 4 + rr;
        const int c = wn * 64 + ni * 16 + llo;
        dst[(size_t)(i0 + r) * kDA + j0 + c] = acc[mi][ni][rr];
      }
}

// ---------------------------------------------------------------------------
// K5 finale: out[i] = [N(u-1)^2 + 2(u-1)U1 + U2 - (4/D)((u-1)xs + xt)
//                      + (4/D^2) q] / N,  q = x.P_offdiag + sum x^2 Mdiag.
// One wave per row.
// ---------------------------------------------------------------------------
__global__ __launch_bounds__(256) void finale_kernel(
    const float* __restrict__ samples, const float* __restrict__ Pslab,
    const float* __restrict__ Mdiag, const float* __restrict__ uarr,
    const float* __restrict__ consts, float* __restrict__ out)
{
  const int row  = blockIdx.x * 4 + (threadIdx.x >> 6);
  const int lane = threadIdx.x & 63;
  const float* P0 = Pslab + (size_t)row * kDA;
  const float* P1 = Pslab + (size_t)(kN + row) * kDA;

  const float4 x  = *(const float4*)(samples + (size_t)row * kD + lane * 4);
  const float4 pa = *(const float4*)(P0 + lane * 4);
  const float4 pb = *(const float4*)(P1 + lane * 4);
  const float4 md = *(const float4*)(Mdiag + lane * 4);

  float q = x.x * (pa.x + pb.x + x.x * md.x) + x.y * (pa.y + pb.y + x.y * md.y) +
            x.z * (pa.z + pb.z + x.z * md.z) + x.w * (pa.w + pb.w + x.w * md.w);
#pragma unroll
  for (int m = 32; m >= 1; m >>= 1) q += __shfl_xor(q, m);

  if (lane == 0) {
    const float xs = P0[256] + P1[256];
    const float xt = P0[257] + P1[257];
    const float um1 = uarr[row] - 1.0f;
    const float U1 = consts[0], U2 = consts[1];
    const float dense = 8192.0f * um1 * um1 + 2.0f * um1 * U1 + U2
                        - 0.015625f * (um1 * xs + xt)        // 4/D
                        + 6.103515625e-05f * q;              // 4/D^2
    out[row] = dense * 1.220703125e-04f;                     // 1/N
  }
}

// ---------------------------------------------------------------------------
// K6 corr: exact-f32 id-pair correction  out[i] += sum_{id_j=id_i}(2S_ij-1)/N
// (incl. diagonal). 16-lane groups per pair (R2-proven).
// ---------------------------------------------------------------------------
__global__ __launch_bounds__(256) void corr_kernel(
    const float* __restrict__ samples, const float* __restrict__ uarr,
    const int* __restrict__ bcount, const int* __restrict__ brows,
    float* __restrict__ out)
{
  const int b = blockIdx.x;
  int cnt = bcount[b];
  if (cnt <= 0) return;
  if (cnt > 128) cnt = 128;
  const int tot = cnt * cnt;
  const int g = threadIdx.x >> 4, gl = threadIdx.x & 15;

  for (int p = g; p < tot; p += 16) {
    const int ia = brows[b * 128 + p / cnt];
    const int jb = brows[b * 128 + p % cnt];
    const float4* xa = (const float4*)(samples + (size_t)ia * kD) + gl * 4;
    const float4* xb = (const float4*)(samples + (size_t)jb * kD) + gl * 4;
    float dot = 0.f;
#pragma unroll
    for (int k = 0; k < 4; ++k) {
      const float4 va = xa[k], vb = xb[k];
      dot += va.x * vb.x + va.y * vb.y + va.z * vb.z + va.w * vb.w;
    }
    dot += __shfl_xor(dot, 1);
    dot += __shfl_xor(dot, 2);
    dot += __shfl_xor(dot, 4);
    dot += __shfl_xor(dot, 8);
    if (gl == 0) {
      const float s = uarr[ia] + uarr[jb] - dot * 0.0078125f;  // 2/D
      atomicAdd(&out[ia], (2.f * s - 1.f) * 1.220703125e-04f);
    }
  }
}

// ---------------------------------------------------------------------------
extern "C" void kernel_launch(void* const* d_in, const int* in_sizes, int n_in,
                              void* d_out, int out_size, void* d_ws, size_t ws_size,
                              hipStream_t stream) {
  const float* samples = (const float*)d_in[0];
  const float* input1  = (const float*)d_in[1];
  float* out = (float*)d_out;

  char* ws = (char*)d_ws;
  size_t off = 0;
  u16*   Xaug  = (u16*)(ws + off);  off += (size_t)kN * kDA * 2;        // 6.3 MB
  u16*   XT    = (u16*)(ws + off);  off += (size_t)kDA * kN * 2;        // 6.3 MB
  float* slabM = (float*)(ws + off); off += (size_t)288 * 16384 * 4;    // 18.9 MB
  u16*   Mhat  = (u16*)(ws + off);  off += (size_t)kDA * kDA * 2;       // 295 KB
  float* Mdiag = (float*)(ws + off); off += 256 * 4;
  float* consts = (float*)(ws + off); off += 256;                        // pad
  float* uarr  = (float*)(ws + off); off += (size_t)kN * 4;
  float* Pslab = (float*)(ws + off); off += (size_t)2 * kN * kDA * 4;   // 25 MB
  int*   bcount = (int*)(ws + off);  off += 1024 * 4;
  int*   brows  = (int*)(ws + off);  off += (size_t)1024 * 128 * 4;

  hipMemsetAsync(bcount, 0, 1024 * sizeof(int), stream);

  prep_kernel<<<kN / 4, 256, 0, stream>>>(samples, input1, Xaug, uarr, bcount, brows);
  transpose_kernel<<<kN / 64, 256, 0, stream>>>(Xaug, XT);
  syrk_kernel<<<dim3(9, 32), 256, 0, stream>>>(XT, slabM);
  reduceM_kernel<<<(kDA * kDA) / 256, 256, 0, stream>>>(slabM, Mhat, Mdiag, consts);
  pgemm_kernel<<<dim3(64, 3, 2), 256, 0, stream>>>(Xaug, Mhat, Pslab);
  finale_kernel<<<kN / 4, 256, 0, stream>>>(samples, Pslab, Mdiag, uarr, consts, out);
  corr_kernel<<<1024, 256, 0, stream>>>(samples, uarr, bcount, brows, out);
}